// Round 11
// baseline (883.366 us; speedup 1.0000x reference)
//
#include <hip/hip_runtime.h>

typedef float v4f __attribute__((ext_vector_type(4)));
static constexpr float EPS = 1e-6f;

// DPP partial-sum step: x += dpp_move(x); out-of-bounds lanes contribute 0.
#define DPP_ADD(x, ctrl, rmask)                                               \
  x += __builtin_bit_cast(float, __builtin_amdgcn_update_dpp(                 \
           0, __builtin_bit_cast(int, x), ctrl, rmask, 0xf, true))

#define LVL10(ctrl, rmask, a, b, c, d, e, f, g, h, i, j)                      \
  DPP_ADD(a, ctrl, rmask); DPP_ADD(b, ctrl, rmask); DPP_ADD(c, ctrl, rmask);  \
  DPP_ADD(d, ctrl, rmask); DPP_ADD(e, ctrl, rmask); DPP_ADD(f, ctrl, rmask);  \
  DPP_ADD(g, ctrl, rmask); DPP_ADD(h, ctrl, rmask); DPP_ADD(i, ctrl, rmask);  \
  DPP_ADD(j, ctrl, rmask)

// Full wave64 sum of 10 interleaved chains; lane 63 ends with each total.
#define WAVE_RED10(a, b, c, d, e, f, g, h, i, j)                              \
  do {                                                                        \
    LVL10(0x111, 0xf, a, b, c, d, e, f, g, h, i, j);                          \
    LVL10(0x112, 0xf, a, b, c, d, e, f, g, h, i, j);                          \
    LVL10(0x114, 0xf, a, b, c, d, e, f, g, h, i, j);                          \
    LVL10(0x118, 0xf, a, b, c, d, e, f, g, h, i, j);                          \
    LVL10(0x142, 0xa, a, b, c, d, e, f, g, h, i, j);                          \
    LVL10(0x143, 0xc, a, b, c, d, e, f, g, h, i, j);                          \
  } while (0)

#define WAVE_RED1(a)                                                          \
  do {                                                                        \
    DPP_ADD(a, 0x111, 0xf); DPP_ADD(a, 0x112, 0xf); DPP_ADD(a, 0x114, 0xf);  \
    DPP_ADD(a, 0x118, 0xf); DPP_ADD(a, 0x142, 0xa); DPP_ADD(a, 0x143, 0xc);  \
  } while (0)

__device__ __forceinline__ float rl63(float x) {
  return __builtin_bit_cast(
      float, __builtin_amdgcn_readlane(__builtin_bit_cast(int, x), 63));
}

// Async global->LDS DMA (no register writeback -> sound with regalloc).
#define GLL(idx, slot)                                                        \
  __builtin_amdgcn_global_load_lds(                                           \
      (const __attribute__((address_space(1))) void*)(hb + (size_t)(idx) * 64 + lane), \
      (__attribute__((address_space(3))) void*)&kring[(slot)][0], 4, 0, 0)

// asm ds_read_b128, wave-uniform address -> HW broadcast; counted drains.
#define DSR(dst, a, offb)                                                     \
  asm volatile("ds_read_b128 %0, %1 offset:%2"                                \
               : "=&v"(dst) : "v"(a), "i"(offb))

// 8 reads = this wave's 32-col slice of one k vector -> register bank.
#define DSR8(B, slot)                                                         \
  do {                                                                        \
    unsigned _a = (unsigned)(unsigned long long)                              \
        (__attribute__((address_space(3))) const float*)&kring[(slot)][slice];\
    DSR(B[0], _a, 0);   DSR(B[1], _a, 16);  DSR(B[2], _a, 32);                \
    DSR(B[3], _a, 48);  DSR(B[4], _a, 64);  DSR(B[5], _a, 80);                \
    DSR(B[6], _a, 96);  DSR(B[7], _a, 112);                                   \
  } while (0)

// per-lane own-row element read (counted, no compiler lgkm bookkeeping).
#define DSR1(dst, slot)                                                       \
  do {                                                                        \
    unsigned _a1 = (unsigned)(unsigned long long)                             \
        (__attribute__((address_space(3))) const float*)&kring[(slot)][lane]; \
    asm volatile("ds_read_b32 %0, %1" : "=&v"(dst) : "v"(_a1));               \
  } while (0)

#define SB __builtin_amdgcn_sched_barrier(0)
#define WAIT_LGKM(n)                                                          \
  do { asm volatile("s_waitcnt lgkmcnt(" #n ")" ::: "memory"); SB; } while (0)
#define WAIT_VM(n)                                                            \
  do { asm volatile("s_waitcnt vmcnt(" #n ")" ::: "memory"); SB; } while (0)

#define KEEP8(BK)                                                             \
  asm volatile("" :: "v"(BK[0]), "v"(BK[1]), "v"(BK[2]), "v"(BK[3]),          \
                     "v"(BK[4]), "v"(BK[5]), "v"(BK[6]), "v"(BK[7]))

// PAIR(UA,UB,NA,NB): UA/UB = REGISTER banks (k_t, k_{t+1}) for the M-update;
// NA/NB = dot banks (k_{t+2}, k_{t+3}), ds_reads in flight since last pair.
// Entry lgkm queue = [NA x8, NB x8, eFp, eGp]. After the update, UA/UB are
// dead and get refilled with slots t+4,t+5 (next pair's dot banks).
#define PAIR(UA, UB, NA, NB)                                                  \
  do {                                                                        \
    /* spec + Gram products: registers only, run during NA/NB drain */        \
    float vp0 = A;                        /* vp_{t+1} | g_t=0 */              \
    float vp1 = fmaf(C_cur, u, A);        /* vp_{t+1} | g_t=1 */              \
    float u0 = fmaf(-r_nxt, vp0, e1);                                         \
    float u1 = fmaf(-r_nxt, vp1, e1);                                         \
    float wz = u  * fmaf(s2_cur, u,  2.0f * vp);                              \
    float z0 = u0 * fmaf(s2_nxt, u0, 2.0f * vp0);                             \
    float z1 = u1 * fmaf(s2_nxt, u1, 2.0f * vp1);                             \
    float pS2a = e2 * e2, pS2b = e3 * e3;                                     \
    float pC2 = e2 * e3, pX02 = e2 * e4, pC3 = e3 * e4;                       \
    float pX03 = e2 * e5, pX13 = e3 * e5;                                     \
    WAIT_LGKM(10);  /* NA landed (leaves NB x8 + eFp,eGp) */                  \
    float D1own, D2own;                                                       \
    {                                                                         \
      v4f x0 = v4f{0.f, 0.f, 0.f, 0.f}, x1 = x0, x2 = x0, x3 = x0;            \
      x0 = __builtin_elementwise_fma(m4[0], NA[0], x0);                       \
      x1 = __builtin_elementwise_fma(m4[1], NA[1], x1);                       \
      x2 = __builtin_elementwise_fma(m4[2], NA[2], x2);                       \
      x3 = __builtin_elementwise_fma(m4[3], NA[3], x3);                       \
      x0 = __builtin_elementwise_fma(m4[4], NA[4], x0);                       \
      x1 = __builtin_elementwise_fma(m4[5], NA[5], x1);                       \
      x2 = __builtin_elementwise_fma(m4[6], NA[6], x2);                       \
      x3 = __builtin_elementwise_fma(m4[7], NA[7], x3);                       \
      v4f xs = (x0 + x1) + (x2 + x3);                                         \
      D1own = (xs.x + xs.y) + (xs.z + xs.w);                                  \
    }                                                                         \
    WAIT_LGKM(2);   /* NB landed (leaves eFp,eGp) */                          \
    {                                                                         \
      v4f y0 = v4f{0.f, 0.f, 0.f, 0.f}, y1 = y0, y2 = y0, y3 = y0;            \
      y0 = __builtin_elementwise_fma(m4[0], NB[0], y0);                       \
      y1 = __builtin_elementwise_fma(m4[1], NB[1], y1);                       \
      y2 = __builtin_elementwise_fma(m4[2], NB[2], y2);                       \
      y3 = __builtin_elementwise_fma(m4[3], NB[3], y3);                       \
      y0 = __builtin_elementwise_fma(m4[4], NB[4], y0);                       \
      y1 = __builtin_elementwise_fma(m4[5], NB[5], y1);                       \
      y2 = __builtin_elementwise_fma(m4[6], NB[6], y2);                       \
      y3 = __builtin_elementwise_fma(m4[7], NB[7], y3);                       \
      v4f ys = (y0 + y1) + (y2 + y3);                                         \
      D2own = (ys.x + ys.y) + (ys.z + ys.w);                                  \
    }                                                                         \
    pdx[par][w][lane] = make_float2(D1own, D2own);                            \
    WAVE_RED10(wz, z0, z1, pS2a, pS2b, pC2, pX02, pC3, pX03, pX13);           \
    asm volatile("s_waitcnt lgkmcnt(0)" ::: "memory");  /* write + eF,eG */   \
    __builtin_amdgcn_s_barrier();                                             \
    SB;                                                                       \
    float2 po = pdx[par][w ^ 1][lane];                                        \
    float zt = rl63(wz);                                                      \
    float z0s = rl63(z0), z1s = rl63(z1);                                     \
    float s2a = rl63(pS2a), s2b = rl63(pS2b);                                 \
    float C2s = rl63(pC2), X02n = rl63(pX02), C3s = rl63(pC3);                \
    float X03n = rl63(pX03), X13n = rl63(pX13);                               \
    bool gt = zt > 0.f;                                                       \
    float zsel = gt ? z1s : z0s;                                              \
    bool gt1 = zsel > 0.f;                                                    \
    float ga = gt ? u : 0.f;                /* g_t * u_t */                   \
    float usel = gt ? u1 : u0;                                                \
    float gb = gt1 ? usel : 0.f;            /* g_{t+1} * u_{t+1} */           \
    float r2 = 1.0f / (s2a + EPS);                                            \
    float D1 = D1own + po.x;                                                  \
    float D2 = D2own + po.y;                                                  \
    float vp_n = fmaf(C_nxt, gb, fmaf(X02, ga, D1));  /* vp_{t+2} */          \
    float A_n  = fmaf(X13,  gb, fmaf(X03, ga, D2));   /* M_{t+2} k_{t+3} */   \
    float u_n  = fmaf(-r2, vp_n, e2);                 /* u_{t+2} */           \
    {                                                                         \
      v4f gav = {ga, ga, ga, ga};                                             \
      _Pragma("unroll")                                                       \
      for (int q = 0; q < 8; ++q)           /* M += g_t u_t k_t^T */          \
        m4[q] = __builtin_elementwise_fma(gav, UA[q], m4[q]);                 \
      v4f gbv = {gb, gb, gb, gb};                                             \
      _Pragma("unroll")                                                       \
      for (int q = 0; q < 8; ++q)           /* M += g_{t+1} u_{t+1} k^T */    \
        m4[q] = __builtin_elementwise_fma(gbv, UB[q], m4[q]);                 \
    }                                                                         \
    WAIT_VM(6);     /* ring slots <= t+9 landed */                            \
    SB;                                                                       \
    DSR8(UA, (t + 4) & 31);   /* UA dead -> next pair's NA */                 \
    DSR8(UB, (t + 5) & 31);                                                   \
    e1 = e3; e2 = e4; e3 = e5; e4 = eFp; e5 = eGp;  /* consume old eF,eG */   \
    DSR1(eFp, (t + 8) & 31);  /* issue next pair's e prefetch */              \
    DSR1(eGp, (t + 9) & 31);                                                  \
    {                                                                         \
      int i0 = t + 16; if (i0 > LM1) i0 = LM1;                                \
      int i1 = t + 17; if (i1 > LM1) i1 = LM1;                                \
      GLL(i0, (t + 16) & 31);                                                 \
      GLL(i1, (t + 17) & 31);                                                 \
    }                                                                         \
    SB;                                                                       \
    vp = vp_n; u = u_n; A = A_n;                                              \
    s2_cur = s2a; s2_nxt = s2b; r_nxt = 1.0f / (s2b + EPS);                   \
    C_cur = C2s; C_nxt = C3s; X02 = X02n; X03 = X03n; X13 = X13n;             \
    par ^= 1; t += 2;                                                         \
  } while (0)

// One block = 2 waves = one batch chain. Lane i owns row i of M; wave w owns
// columns [32w, 32w+32). Scalar/gate state replicated in both waves; partial
// dots exchanged through LDS once per pair. Algebra identical to R9/R10.
__global__ __launch_bounds__(128, 1)
void delta_mem_seq(const float* __restrict__ h,
                   const float* __restrict__ W,
                   const float* __restrict__ bias,
                   float* __restrict__ out,
                   int L) {
  const int tid = threadIdx.x;
  const int w = tid >> 6;
  const int lane = tid & 63;
  const int slice = w << 5;
  __shared__ alignas(16) float kring[32][64];
  __shared__ float2 pdx[2][2][64];
  __shared__ alignas(16) float rbuf[64];
  const float* __restrict__ hb = h + (size_t)blockIdx.x * (size_t)L * 64;
  const int LM1 = L - 1;  // gates t = 0..LM1-1

  v4f m4[8];  // M[lane][32w .. 32w+31]
#pragma unroll
  for (int q = 0; q < 8; ++q) m4[q] = v4f{0.f, 0.f, 0.f, 0.f};

  // Prologue: fill ring slots 0..15 (both waves duplicate -> wave-local vmcnt).
#pragma unroll
  for (int i = 0; i < 16; ++i) {
    int idx = (i <= LM1) ? i : LM1;
    GLL(idx, i);
  }
  WAIT_VM(0);

  float e0 = kring[0][lane];
  float e1 = kring[1][lane], e2 = kring[2][lane], e3 = kring[3][lane];
  float e4 = kring[4][lane], e5 = kring[5][lane];

  // Prologue reductions: s2_0, s2_1, C_0, C_1, X02, X03, X13.
  float c0 = e0 * e0, c1 = e1 * e1, c2 = e0 * e1, c3 = e1 * e2;
  float c4 = e0 * e2, c5 = e0 * e3, c6 = e1 * e3;
  float c7 = 0.f, c8 = 0.f, c9 = 0.f;
  WAVE_RED10(c0, c1, c2, c3, c4, c5, c6, c7, c8, c9);
  float s2_cur = rl63(c0), s2_nxt = rl63(c1);
  float C_cur = rl63(c2), C_nxt = rl63(c3);
  float X02 = rl63(c4), X03 = rl63(c5), X13 = rl63(c6);
  float r_nxt = 1.0f / (s2_nxt + EPS);
  float vp = 0.f;  // vp_0 = M_0 k_0 = 0
  float u = e0;    // u_0 = k_0
  float A = 0.f;   // M_0 k_1 = 0
  int par = 0;
  int t = 0;

  // Register bank prefetch: U = slots 0,1 (first update), drained here;
  // N = slots 2,3 + e-prefetch slots 6,7 left IN FLIGHT (first pair drains).
  v4f U0[8], U1[8], N0[8], N1[8];
  float eFp, eGp;
  SB;
  DSR8(U0, 0);
  DSR8(U1, 1);
  WAIT_LGKM(0);  // U drained (first pair's update source)
  DSR8(N0, 2);
  DSR8(N1, 3);
  DSR1(eFp, 6);
  DSR1(eGp, 7);
  SB;            // queue = [N0 x8, N1 x8, eFp, eGp] = loop invariant

  while (t + 3 < LM1) {   // 2x unrolled bank-role rotation
    PAIR(U0, U1, N0, N1);
    PAIR(N0, N1, U0, U1);
  }
  if (t + 1 < LM1) PAIR(U0, U1, N0, N1);

  // Drain ALL in-flight ds_reads/DMAs; keep dst registers formally live so
  // regalloc cannot recycle them under a pending writeback (R5-R7 lesson).
  asm volatile("s_waitcnt vmcnt(0) lgkmcnt(0)" ::: "memory");
  SB;
  KEEP8(U0); KEEP8(U1); KEEP8(N0); KEEP8(N1);
  asm volatile("" :: "v"(eFp), "v"(eGp));

  if (t < LM1) {  // odd leftover gate: no M-update needed
    float wz = u * fmaf(s2_cur, u, 2.0f * vp);
    WAVE_RED1(wz);
    float zt = rl63(wz);
    float coef = (zt > 0.f) ? C_cur : 0.f;
    vp = fmaf(coef, u, A);  // read = M_L k_{L-1}
  }

  if (w == 0) rbuf[lane] = vp;
  __syncthreads();

  if (w == 0) {
    const v4f* wv = (const v4f*)(W + lane * 64);
    const v4f* rv = (const v4f*)rbuf;
    v4f acc = v4f{0.f, 0.f, 0.f, 0.f};
#pragma unroll
    for (int q = 0; q < 16; ++q)
      acc = __builtin_elementwise_fma(wv[q], rv[q], acc);
    out[(size_t)blockIdx.x * 64 + lane] =
        bias[lane] + ((acc.x + acc.y) + (acc.z + acc.w));
  }
}

extern "C" void kernel_launch(void* const* d_in, const int* in_sizes, int n_in,
                              void* d_out, int out_size, void* d_ws, size_t ws_size,
                              hipStream_t stream) {
  const float* h    = (const float*)d_in[0];
  const float* W    = (const float*)d_in[1];
  const float* bias = (const float*)d_in[2];
  float* out = (float*)d_out;

  const int H = in_sizes[2];            // 64
  const int B = out_size / H;           // 256
  const int L = in_sizes[0] / (B * H);  // 2048

  delta_mem_seq<<<B, 128, 0, stream>>>(h, W, bias, out, L);
}

// Round 12
// 718.512 us; speedup vs baseline: 1.2294x; 1.2294x over previous
//
#include <hip/hip_runtime.h>

typedef float v4f __attribute__((ext_vector_type(4)));
typedef float v2f __attribute__((ext_vector_type(2)));
static constexpr float EPS = 1e-6f;

// DPP partial-sum step: x += dpp_move(x); out-of-bounds lanes contribute 0.
#define DPP_ADD(x, ctrl, rmask)                                               \
  x += __builtin_bit_cast(float, __builtin_amdgcn_update_dpp(                 \
           0, __builtin_bit_cast(int, x), ctrl, rmask, 0xf, true))

#define LVL10(ctrl, rmask, a, b, c, d, e, f, g, h, i, j)                      \
  DPP_ADD(a, ctrl, rmask); DPP_ADD(b, ctrl, rmask); DPP_ADD(c, ctrl, rmask);  \
  DPP_ADD(d, ctrl, rmask); DPP_ADD(e, ctrl, rmask); DPP_ADD(f, ctrl, rmask);  \
  DPP_ADD(g, ctrl, rmask); DPP_ADD(h, ctrl, rmask); DPP_ADD(i, ctrl, rmask);  \
  DPP_ADD(j, ctrl, rmask)

#define WAVE_RED10(a, b, c, d, e, f, g, h, i, j)                              \
  do {                                                                        \
    LVL10(0x111, 0xf, a, b, c, d, e, f, g, h, i, j);                          \
    LVL10(0x112, 0xf, a, b, c, d, e, f, g, h, i, j);                          \
    LVL10(0x114, 0xf, a, b, c, d, e, f, g, h, i, j);                          \
    LVL10(0x118, 0xf, a, b, c, d, e, f, g, h, i, j);                          \
    LVL10(0x142, 0xa, a, b, c, d, e, f, g, h, i, j);                          \
    LVL10(0x143, 0xc, a, b, c, d, e, f, g, h, i, j);                          \
  } while (0)

#define WAVE_RED3(a, b, c)                                                    \
  do {                                                                        \
    DPP_ADD(a, 0x111, 0xf); DPP_ADD(b, 0x111, 0xf); DPP_ADD(c, 0x111, 0xf);  \
    DPP_ADD(a, 0x112, 0xf); DPP_ADD(b, 0x112, 0xf); DPP_ADD(c, 0x112, 0xf);  \
    DPP_ADD(a, 0x114, 0xf); DPP_ADD(b, 0x114, 0xf); DPP_ADD(c, 0x114, 0xf);  \
    DPP_ADD(a, 0x118, 0xf); DPP_ADD(b, 0x118, 0xf); DPP_ADD(c, 0x118, 0xf);  \
    DPP_ADD(a, 0x142, 0xa); DPP_ADD(b, 0x142, 0xa); DPP_ADD(c, 0x142, 0xa);  \
    DPP_ADD(a, 0x143, 0xc); DPP_ADD(b, 0x143, 0xc); DPP_ADD(c, 0x143, 0xc);  \
  } while (0)

#define WAVE_RED2(a, b)                                                       \
  do {                                                                        \
    DPP_ADD(a, 0x111, 0xf); DPP_ADD(b, 0x111, 0xf);                           \
    DPP_ADD(a, 0x112, 0xf); DPP_ADD(b, 0x112, 0xf);                           \
    DPP_ADD(a, 0x114, 0xf); DPP_ADD(b, 0x114, 0xf);                           \
    DPP_ADD(a, 0x118, 0xf); DPP_ADD(b, 0x118, 0xf);                           \
    DPP_ADD(a, 0x142, 0xa); DPP_ADD(b, 0x142, 0xa);                           \
    DPP_ADD(a, 0x143, 0xc); DPP_ADD(b, 0x143, 0xc);                           \
  } while (0)

#define WAVE_RED1(a)                                                          \
  do {                                                                        \
    DPP_ADD(a, 0x111, 0xf); DPP_ADD(a, 0x112, 0xf); DPP_ADD(a, 0x114, 0xf);  \
    DPP_ADD(a, 0x118, 0xf); DPP_ADD(a, 0x142, 0xa); DPP_ADD(a, 0x143, 0xc);  \
  } while (0)

__device__ __forceinline__ float rl63(float x) {
  return __builtin_bit_cast(
      float, __builtin_amdgcn_readlane(__builtin_bit_cast(int, x), 63));
}

// Async global->LDS DMA (no register writeback -> sound with regalloc).
#define GLL(idx, slot)                                                        \
  __builtin_amdgcn_global_load_lds(                                           \
      (const __attribute__((address_space(1))) void*)(hb + (size_t)(idx) * 64 + lane), \
      (__attribute__((address_space(3))) void*)&kring[(slot)][0], 4, 0, 0)

// asm LDS ops; counted lgkm drains; every dst drained before any use.
#define DSR(dst, a, offb)                                                     \
  asm volatile("ds_read_b128 %0, %1 offset:%2"                                \
               : "=&v"(dst) : "v"(a), "i"(offb))
#define DSRB128(dst, a, offb)                                                 \
  asm volatile("ds_read_b128 %0, %1 offset:%2"                                \
               : "=&v"(dst) : "v"(a), "i"(offb))
#define DSRB64(dst, a, offb)                                                  \
  asm volatile("ds_read_b64 %0, %1 offset:%2"                                 \
               : "=&v"(dst) : "v"(a), "i"(offb))
#define DSW64(a, d, offb)                                                     \
  asm volatile("ds_write_b64 %0, %1 offset:%2"                                \
               :: "v"(a), "v"(d), "i"(offb) : "memory")
#define DSW32(a, d, offb)                                                     \
  asm volatile("ds_write_b32 %0, %1 offset:%2"                                \
               :: "v"(a), "v"(d), "i"(offb) : "memory")

// 4 reads = this wave's 16-col slice of one k vector -> register bank.
#define DSR4(B, slot)                                                         \
  do {                                                                        \
    unsigned _a = kb + (unsigned)(slot) * 256u + woff;                        \
    DSR(B[0], _a, 0); DSR(B[1], _a, 16); DSR(B[2], _a, 32); DSR(B[3], _a, 48);\
  } while (0)
#define DSR1(dst, slot)                                                       \
  do {                                                                        \
    unsigned _a1 = kb + (unsigned)(slot) * 256u + laneb;                      \
    asm volatile("ds_read_b32 %0, %1" : "=&v"(dst) : "v"(_a1));               \
  } while (0)

#define SB __builtin_amdgcn_sched_barrier(0)
#define WAIT_LGKM(n)                                                          \
  do { asm volatile("s_waitcnt lgkmcnt(" #n ")" ::: "memory"); SB; } while (0)
#define WAIT_VM(n)                                                            \
  do { asm volatile("s_waitcnt vmcnt(" #n ")" ::: "memory"); SB; } while (0)
#define KEEP4(BK)                                                             \
  asm volatile("" :: "v"(BK[0]), "v"(BK[1]), "v"(BK[2]), "v"(BK[3]))

// PAIR(UA,UB,NA,NB,PAR): UA/UB = register banks k_t,k_{t+1} (M-update);
// NA/NB = dot banks k_{t+2},k_{t+3} (in flight since last pair end).
// Entry lgkm queue = [NA x4, NB x4, eF, eG] (10). One barrier per pair
// carries: dot partials (4-way), 10 reduction scalars (waves split 3/3/2/2,
// lane-63 publishes -> no readlanes). Algebra identical to R9-R11 (passed).
#define PAIR(UA, UB, NA, NB, PAR)                                             \
  do {                                                                        \
    float vp0 = A;                        /* vp_{t+1} | g_t=0 */              \
    float vp1 = fmaf(C_cur, u, A);        /* vp_{t+1} | g_t=1 */              \
    float u0 = fmaf(-r_nxt, vp0, e1);                                         \
    float u1 = fmaf(-r_nxt, vp1, e1);                                         \
    WAIT_LGKM(6);   /* NA landed */                                           \
    float D1own, D2own;                                                       \
    {                                                                         \
      v4f x0 = __builtin_elementwise_fma(m4[0], NA[0], v4f{0.f,0.f,0.f,0.f}); \
      v4f x1 = __builtin_elementwise_fma(m4[1], NA[1], v4f{0.f,0.f,0.f,0.f}); \
      x0 = __builtin_elementwise_fma(m4[2], NA[2], x0);                       \
      x1 = __builtin_elementwise_fma(m4[3], NA[3], x1);                       \
      v4f xs = x0 + x1;                                                       \
      D1own = (xs.x + xs.y) + (xs.z + xs.w);                                  \
    }                                                                         \
    WAIT_LGKM(2);   /* NB landed */                                           \
    {                                                                         \
      v4f y0 = __builtin_elementwise_fma(m4[0], NB[0], v4f{0.f,0.f,0.f,0.f}); \
      v4f y1 = __builtin_elementwise_fma(m4[1], NB[1], v4f{0.f,0.f,0.f,0.f}); \
      y0 = __builtin_elementwise_fma(m4[2], NB[2], y0);                       \
      y1 = __builtin_elementwise_fma(m4[3], NB[3], y1);                       \
      v4f ys = y0 + y1;                                                       \
      D2own = (ys.x + ys.y) + (ys.z + ys.w);                                  \
    }                                                                         \
    DSW64(pdx_w, ((v2f){D1own, D2own}), (PAR) * 2048);                        \
    if (w == 0) {       /* chains: z_t, z_{t+1}|0, z_{t+1}|1 */               \
      float wz = u  * fmaf(s2_cur, u,  2.0f * vp);                            \
      float z0 = u0 * fmaf(s2_nxt, u0, 2.0f * vp0);                           \
      float z1 = u1 * fmaf(s2_nxt, u1, 2.0f * vp1);                           \
      WAVE_RED3(wz, z0, z1);                                                  \
      if (lane == 63) {                                                       \
        DSW64(sc_a, ((v2f){wz, z0}), (PAR) * 48 + 0);                         \
        DSW32(sc_a, z1, (PAR) * 48 + 8);                                      \
      }                                                                       \
    } else if (w == 1) {  /* s2_{t+2}, s2_{t+3}, C_{t+1} */                   \
      float pa = e2 * e2, pb = e3 * e3, pc = e2 * e3;                         \
      WAVE_RED3(pa, pb, pc);                                                  \
      if (lane == 63) {                                                       \
        DSW32(sc_a, pa, (PAR) * 48 + 12);                                     \
        DSW64(sc_a, ((v2f){pb, pc}), (PAR) * 48 + 16);                        \
      }                                                                       \
    } else if (w == 2) {  /* X02', C3' */                                     \
      float pa = e2 * e4, pb = e3 * e4;                                       \
      WAVE_RED2(pa, pb);                                                      \
      if (lane == 63) DSW64(sc_a, ((v2f){pa, pb}), (PAR) * 48 + 24);          \
    } else {              /* X03', X13' */                                    \
      float pa = e2 * e5, pb = e3 * e5;                                       \
      WAVE_RED2(pa, pb);                                                      \
      if (lane == 63) DSW64(sc_a, ((v2f){pa, pb}), (PAR) * 48 + 32);          \
    }                                                                         \
    asm volatile("s_waitcnt lgkmcnt(0)" ::: "memory"); /* all writes out */   \
    __builtin_amdgcn_s_barrier();                                             \
    SB;                                                                       \
    v4f S0, S1; v2f S2, P0, P1, P2;                                           \
    DSRB128(S0, sc_a, (PAR) * 48 + 0);                                        \
    DSRB128(S1, sc_a, (PAR) * 48 + 16);                                       \
    DSRB64(S2, sc_a, (PAR) * 48 + 32);                                        \
    DSRB64(P0, pdx_r0, (PAR) * 2048);                                         \
    DSRB64(P1, pdx_r1, (PAR) * 2048);                                         \
    DSRB64(P2, pdx_r2, (PAR) * 2048);                                         \
    WAIT_LGKM(3);   /* scalars landed */                                      \
    float zt = S0.x, z0s = S0.y, z1s = S0.z, s2a = S0.w;                      \
    float s2b = S1.x, C2s = S1.y, X02n = S1.z, C3s = S1.w;                    \
    bool gt = zt > 0.f;                                                       \
    float zsel = gt ? z1s : z0s;                                              \
    bool gt1 = zsel > 0.f;                                                    \
    float ga = gt ? u : 0.f;                /* g_t * u_t */                   \
    float usel = gt ? u1 : u0;                                                \
    float gb = gt1 ? usel : 0.f;            /* g_{t+1} * u_{t+1} */           \
    float r2 = 1.0f / (s2a + EPS);                                            \
    WAIT_LGKM(0);   /* partials landed */                                     \
    float X03n = S2.x, X13n = S2.y;                                           \
    float D1 = (D1own + P0.x) + (P1.x + P2.x);                                \
    float D2 = (D2own + P0.y) + (P1.y + P2.y);                                \
    float vp_n = fmaf(C_nxt, gb, fmaf(X02, ga, D1));  /* vp_{t+2} */          \
    float A_n  = fmaf(X13,  gb, fmaf(X03, ga, D2));   /* M_{t+2} k_{t+3} */   \
    float u_n  = fmaf(-r2, vp_n, e2);                 /* u_{t+2} */           \
    {                                                                         \
      v4f gav = {ga, ga, ga, ga};                                             \
      m4[0] = __builtin_elementwise_fma(gav, UA[0], m4[0]);                   \
      m4[1] = __builtin_elementwise_fma(gav, UA[1], m4[1]);                   \
      m4[2] = __builtin_elementwise_fma(gav, UA[2], m4[2]);                   \
      m4[3] = __builtin_elementwise_fma(gav, UA[3], m4[3]);                   \
      v4f gbv = {gb, gb, gb, gb};                                             \
      m4[0] = __builtin_elementwise_fma(gbv, UB[0], m4[0]);                   \
      m4[1] = __builtin_elementwise_fma(gbv, UB[1], m4[1]);                   \
      m4[2] = __builtin_elementwise_fma(gbv, UB[2], m4[2]);                   \
      m4[3] = __builtin_elementwise_fma(gbv, UB[3], m4[3]);                   \
    }                                                                         \
    WAIT_VM(6);     /* ring slots <= t+9 landed */                            \
    DSR4(UA, (t + 4) & 31);   /* UA dead -> next pair's NA */                 \
    DSR4(UB, (t + 5) & 31);                                                   \
    e1 = e3; e2 = e4; e3 = e5; e4 = eFp; e5 = eGp;  /* old eF,eG drained */   \
    DSR1(eFp, (t + 8) & 31);                                                  \
    DSR1(eGp, (t + 9) & 31);                                                  \
    {                                                                         \
      int i0 = t + 16; if (i0 > LM1) i0 = LM1;                                \
      int i1 = t + 17; if (i1 > LM1) i1 = LM1;                                \
      GLL(i0, (t + 16) & 31);                                                 \
      GLL(i1, (t + 17) & 31);                                                 \
    }                                                                         \
    SB;                                                                       \
    vp = vp_n; u = u_n; A = A_n;                                              \
    s2_cur = s2a; s2_nxt = s2b; r_nxt = 1.0f / (s2b + EPS);                   \
    C_cur = C2s; C_nxt = C3s; X02 = X02n; X03 = X03n; X13 = X13n;             \
    t += 2;                                                                   \
  } while (0)

// One block = 4 waves = one batch chain. Lane i owns row i of M; wave w owns
// columns [16w, 16w+16). Scalar/gate state replicated; reduction chains are
// SPLIT across waves (3/3/2/2) and published through LDS at the pair barrier.
__global__ __launch_bounds__(256, 1)
void delta_mem_seq(const float* __restrict__ h,
                   const float* __restrict__ W,
                   const float* __restrict__ bias,
                   float* __restrict__ out,
                   int L) {
  const int tid = threadIdx.x;
  const int w = tid >> 6;
  const int lane = tid & 63;
  __shared__ alignas(16) float kring[32][64];   // 8 KB ring
  __shared__ alignas(16) v2f pdx[2][4][64];     // dot partials, 4 KB
  __shared__ alignas(16) float scal[2][12];     // published reduction scalars
  __shared__ alignas(16) float rbuf[64];
  const float* __restrict__ hb = h + (size_t)blockIdx.x * (size_t)L * 64;
  const int LM1 = L - 1;  // gates t = 0..LM1-1

  const unsigned kb = (unsigned)(unsigned long long)
      (__attribute__((address_space(3))) const float*)&kring[0][0];
  const unsigned woff = (unsigned)(w << 6);     // 16 floats * 4 B
  const unsigned laneb = (unsigned)(lane << 2);
  const unsigned pb = (unsigned)(unsigned long long)
      (__attribute__((address_space(3))) const v2f*)&pdx[0][0][0];
  const unsigned pdx_w  = pb + (unsigned)(w << 9) + (unsigned)(lane << 3);
  const unsigned pdx_r0 = pb + (unsigned)(((w + 1) & 3) << 9) + (unsigned)(lane << 3);
  const unsigned pdx_r1 = pb + (unsigned)(((w + 2) & 3) << 9) + (unsigned)(lane << 3);
  const unsigned pdx_r2 = pb + (unsigned)(((w + 3) & 3) << 9) + (unsigned)(lane << 3);
  const unsigned sc_a = (unsigned)(unsigned long long)
      (__attribute__((address_space(3))) const float*)&scal[0][0];

  v4f m4[4];  // M[lane][16w .. 16w+15]
#pragma unroll
  for (int q = 0; q < 4; ++q) m4[q] = v4f{0.f, 0.f, 0.f, 0.f};

  // Prologue: fill ring slots 0..15 (all 4 waves duplicate -> wave-local vmcnt).
#pragma unroll
  for (int i = 0; i < 16; ++i) {
    int idx = (i <= LM1) ? i : LM1;
    GLL(idx, i);
  }
  WAIT_VM(0);

  float e0 = kring[0][lane];
  float e1 = kring[1][lane], e2 = kring[2][lane], e3 = kring[3][lane];
  float e4 = kring[4][lane], e5 = kring[5][lane];

  // Prologue reductions (replicated, once): s2_0,s2_1,C_0,C_1,X02,X03,X13.
  float c0 = e0 * e0, c1 = e1 * e1, c2 = e0 * e1, c3 = e1 * e2;
  float c4 = e0 * e2, c5 = e0 * e3, c6 = e1 * e3;
  float c7 = 0.f, c8 = 0.f, c9 = 0.f;
  WAVE_RED10(c0, c1, c2, c3, c4, c5, c6, c7, c8, c9);
  float s2_cur = rl63(c0), s2_nxt = rl63(c1);
  float C_cur = rl63(c2), C_nxt = rl63(c3);
  float X02 = rl63(c4), X03 = rl63(c5), X13 = rl63(c6);
  float r_nxt = 1.0f / (s2_nxt + EPS);
  float vp = 0.f;  // vp_0 = M_0 k_0 = 0
  float u = e0;    // u_0 = k_0
  float A = 0.f;   // M_0 k_1 = 0
  int t = 0;

  // Register banks: U = slots 0,1 (first update), drained; N = slots 2,3 and
  // e-prefetch slots 6,7 left IN FLIGHT -> loop-entry queue = 10.
  v4f U0[4], U1[4], N0[4], N1[4];
  float eFp, eGp;
  SB;
  DSR4(U0, 0);
  DSR4(U1, 1);
  WAIT_LGKM(0);  // U drained + any prologue C++ LDS stragglers
  DSR4(N0, 2);
  DSR4(N1, 3);
  DSR1(eFp, 6);
  DSR1(eGp, 7);
  SB;            // queue = [N0 x4, N1 x4, eFp, eGp]

  while (t + 3 < LM1) {   // 2x unrolled bank-role rotation; PAR alternates
    PAIR(U0, U1, N0, N1, 0);
    PAIR(N0, N1, U0, U1, 1);
  }
  if (t + 1 < LM1) PAIR(U0, U1, N0, N1, 0);

  // Drain ALL in-flight ds_reads/DMAs; keep dsts formally live (R5-R7 lesson).
  asm volatile("s_waitcnt vmcnt(0) lgkmcnt(0)" ::: "memory");
  SB;
  KEEP4(U0); KEEP4(U1); KEEP4(N0); KEEP4(N1);
  asm volatile("" :: "v"(eFp), "v"(eGp));

  if (t < LM1) {  // odd leftover gate (replicated in all waves)
    float wz = u * fmaf(s2_cur, u, 2.0f * vp);
    WAVE_RED1(wz);
    float zt = rl63(wz);
    float coef = (zt > 0.f) ? C_cur : 0.f;
    vp = fmaf(coef, u, A);  // read = M_L k_{L-1}
  }

  if (w == 0) rbuf[lane] = vp;
  __syncthreads();

  if (w == 0) {
    const v4f* wv = (const v4f*)(W + lane * 64);
    const v4f* rv = (const v4f*)rbuf;
    v4f acc = v4f{0.f, 0.f, 0.f, 0.f};
#pragma unroll
    for (int q = 0; q < 16; ++q)
      acc = __builtin_elementwise_fma(wv[q], rv[q], acc);
    out[(size_t)blockIdx.x * 64 + lane] =
        bias[lane] + ((acc.x + acc.y) + (acc.z + acc.w));
  }
}

extern "C" void kernel_launch(void* const* d_in, const int* in_sizes, int n_in,
                              void* d_out, int out_size, void* d_ws, size_t ws_size,
                              hipStream_t stream) {
  const float* h    = (const float*)d_in[0];
  const float* W    = (const float*)d_in[1];
  const float* bias = (const float*)d_in[2];
  float* out = (float*)d_out;

  const int H = in_sizes[2];            // 64
  const int B = out_size / H;           // 256
  const int L = in_sizes[0] / (B * H);  // 2048

  delta_mem_seq<<<B, 256, 0, stream>>>(h, W, bias, out, L);
}